// Round 1
// baseline (120.839 us; speedup 1.0000x reference)
//
#include <hip/hip_runtime.h>

#define BATCH 8
#define CH 3
#define H_OUT 384
#define W_OUT 1280
#define H_IN 96
#define W_IN 320
#define HW_OUT (H_OUT * W_OUT)
#define HW_IN (H_IN * W_IN)

__global__ __launch_bounds__(256) void warp_sceneflow_kernel(
    const float* __restrict__ image,   // (B,3,384,1280)
    const float* __restrict__ disp,    // (B,1,96,320)
    const float* __restrict__ scene,   // (B,3,96,320)
    const float* __restrict__ intrin,  // (B,3,3)
    const float* __restrict__ aug,     // (B,2)
    float* __restrict__ out)           // (B,3,384,1280)
{
    int idx = blockIdx.x * blockDim.x + threadIdx.x;
    if (idx >= BATCH * HW_OUT) return;
    int b = idx / HW_OUT;
    int p = idx - b * HW_OUT;
    int y = p / W_OUT;
    int x = p - y * W_OUT;

    // per-batch scaled intrinsics
    float sy = (float)H_OUT / aug[b * 2 + 0];
    float sx = (float)W_OUT / aug[b * 2 + 1];
    float fx = intrin[b * 9 + 0] * sx;
    float fy = intrin[b * 9 + 4] * sy;
    float cx = intrin[b * 9 + 2] * sx;
    float cy = intrin[b * 9 + 5] * sy;

    // align-corners bilinear source coords for the low-res maps
    float ysrc = (float)y * ((float)(H_IN - 1) / (float)(H_OUT - 1));
    float xsrc = (float)x * ((float)(W_IN - 1) / (float)(W_OUT - 1));
    int y0 = (int)floorf(ysrc);
    int x0 = (int)floorf(xsrc);
    int y1 = min(y0 + 1, H_IN - 1);
    int x1 = min(x0 + 1, W_IN - 1);
    float wy = ysrc - (float)y0;
    float wx = xsrc - (float)x0;
    float w00 = (1.0f - wy) * (1.0f - wx);
    float w01 = (1.0f - wy) * wx;
    float w10 = wy * (1.0f - wx);
    float w11 = wy * wx;

    // disp upsample -> depth
    const float* db = disp + b * HW_IN;
    float dval = w00 * db[y0 * W_IN + x0] + w01 * db[y0 * W_IN + x1]
               + w10 * db[y1 * W_IN + x0] + w11 * db[y1 * W_IN + x1];
    float disp_full = dval * (float)W_OUT;
    float depth = fminf(fmaxf(fx * 0.54f / (disp_full + 1e-8f), 0.001f), 80.0f);

    // scene upsample (3 channels, same weights)
    const float* sb = scene + b * (CH * HW_IN);
    float sc0, sc1, sc2;
    {
        const float* s = sb;
        sc0 = w00 * s[y0 * W_IN + x0] + w01 * s[y0 * W_IN + x1]
            + w10 * s[y1 * W_IN + x0] + w11 * s[y1 * W_IN + x1];
        s = sb + HW_IN;
        sc1 = w00 * s[y0 * W_IN + x0] + w01 * s[y0 * W_IN + x1]
            + w10 * s[y1 * W_IN + x0] + w11 * s[y1 * W_IN + x1];
        s = sb + 2 * HW_IN;
        sc2 = w00 * s[y0 * W_IN + x0] + w01 * s[y0 * W_IN + x1]
            + w10 * s[y1 * W_IN + x0] + w11 * s[y1 * W_IN + x1];
    }

    // backproject (Kinv analytic) + scene flow
    float X = ((float)x - cx) / fx * depth + sc0;
    float Y = ((float)y - cy) / fy * depth + sc1;
    float Z = depth + sc2;

    // reproject
    float u = fx * X + cx * Z;
    float v = fy * Y + cy * Z;
    float rw = 1.0f / (Z + 1e-8f);
    float coord_x = u * rw;
    float coord_y = v * rw;

    // normalize round-trip (matches reference arithmetic; cancels numerically)
    float nx = coord_x / (float)(W_OUT - 1) * 2.0f - 1.0f;
    float ny = coord_y / (float)(H_OUT - 1) * 2.0f - 1.0f;
    float gx = (nx + 1.0f) * 0.5f * (float)(W_OUT - 1);
    float gy = (ny + 1.0f) * 0.5f * (float)(H_OUT - 1);

    // grid sample, zeros padding, bilinear
    float gx0f = floorf(gx), gy0f = floorf(gy);
    float fwx = gx - gx0f, fwy = gy - gy0f;
    int ix0 = (int)gx0f, iy0 = (int)gy0f;
    int ix1 = ix0 + 1, iy1 = iy0 + 1;
    bool vx0 = (ix0 >= 0) && (ix0 <= W_OUT - 1);
    bool vx1 = (ix1 >= 0) && (ix1 <= W_OUT - 1);
    bool vy0 = (iy0 >= 0) && (iy0 <= H_OUT - 1);
    bool vy1 = (iy1 >= 0) && (iy1 <= H_OUT - 1);
    int cx0 = min(max(ix0, 0), W_OUT - 1);
    int cx1 = min(max(ix1, 0), W_OUT - 1);
    int cy0 = min(max(iy0, 0), H_OUT - 1);
    int cy1 = min(max(iy1, 0), H_OUT - 1);
    float m00 = (vx0 && vy0) ? 1.0f : 0.0f;
    float m01 = (vx1 && vy0) ? 1.0f : 0.0f;
    float m10 = (vx0 && vy1) ? 1.0f : 0.0f;
    float m11 = (vx1 && vy1) ? 1.0f : 0.0f;
    float g00 = (1.0f - fwy) * (1.0f - fwx) * m00;
    float g01 = (1.0f - fwy) * fwx * m01;
    float g10 = fwy * (1.0f - fwx) * m10;
    float g11 = fwy * fwx * m11;

    const float* ib = image + b * (CH * HW_OUT);
    float* ob = out + b * (CH * HW_OUT);
    int o00 = cy0 * W_OUT + cx0;
    int o01 = cy0 * W_OUT + cx1;
    int o10 = cy1 * W_OUT + cx0;
    int o11 = cy1 * W_OUT + cx1;
    #pragma unroll
    for (int c = 0; c < CH; ++c) {
        const float* im = ib + c * HW_OUT;
        float r = g00 * im[o00] + g01 * im[o01] + g10 * im[o10] + g11 * im[o11];
        ob[c * HW_OUT + p] = r;
    }
}

extern "C" void kernel_launch(void* const* d_in, const int* in_sizes, int n_in,
                              void* d_out, int out_size, void* d_ws, size_t ws_size,
                              hipStream_t stream) {
    const float* image  = (const float*)d_in[0];
    const float* disp   = (const float*)d_in[1];
    const float* scene  = (const float*)d_in[2];
    const float* intrin = (const float*)d_in[3];
    const float* aug    = (const float*)d_in[4];
    float* out = (float*)d_out;

    const int total = BATCH * HW_OUT;
    const int block = 256;
    const int grid = (total + block - 1) / block;
    warp_sceneflow_kernel<<<grid, block, 0, stream>>>(image, disp, scene, intrin, aug, out);
}